// Round 12
// baseline (195.103 us; speedup 1.0000x reference)
//
#include <hip/hip_runtime.h>
#include <math.h>

// Problem dims
#define BSZ   256
#define LDIM  128
#define PDIM  3
#define HDIM  512
#define DDIM  32
#define NDIM  50
#define NEDGE 1225   // N*(N-1)/2
#define EOUT  5      // EDIM+1
#define NRH   8      // r-chunks of 64 cols
#define ECH   64     // cols per chunk

// out layout (floats)
//   node_logits  [256,50,32]   @ 0        (409600)
//   edge_logits  [256,1225,5]  @ 409600   (1568000)
//   size_probs   [256,50]      @ 1977600  (12800)
//   edge_indices [1225,2]      @ 1990400  (2450, float values)
// ws layout (floats): u @0 (131072), pW1 @131072 (25600), n1 @156672 (131072),
//                     P @287744 (8 x 1568000 = 12544000)

// ============ k_pre: 256-thr blocks, col-split roles (round-11, proven) ====
__global__ __launch_bounds__(256) void k_pre(
        const float* __restrict__ z, const float* __restrict__ tp,
        const float* __restrict__ W_in, const float* __restrict__ b_in,
        const float* __restrict__ W_s1, const float* __restrict__ b_s1,
        const float* __restrict__ W_s2, const float* __restrict__ b_s2,
        const float* __restrict__ W_n1, const float* __restrict__ b_n1,
        const float* __restrict__ W_e1, const float* __restrict__ pe,
        float* __restrict__ n1, float* __restrict__ u,
        float* __restrict__ pW1, float* __restrict__ out_sp) {
    int bx = blockIdx.x, t = threadIdx.x;
    __shared__ float smem[2368];

    if (bx < 512) {
        int role = bx >> 8;
        int idx2 = bx & 255;
        int bg = idx2 >> 1, jh = idx2 & 1;
        int b0 = bg * 2;
        float* sin_ = smem;            // [2][132]
        float* sh   = smem + 264;      // [2][512]
        for (int q = t; q < 2 * 131; q += 256) {
            int bi = q / 131, k = q % 131;
            sin_[bi * 132 + k] = (k < LDIM) ? z[(size_t)(b0 + bi) * LDIM + k]
                                            : tp[(size_t)(b0 + bi) * PDIM + (k - LDIM)];
        }
        __syncthreads();
        {
            float bi0 = b_in[t], bi1 = b_in[t + 256];
            float a00 = bi0, a01 = bi1, a10 = bi0, a11 = bi1;
            for (int k = 0; k < LDIM + PDIM; ++k) {
                float w0 = W_in[(size_t)k * HDIM + t];
                float w1 = W_in[(size_t)k * HDIM + t + 256];
                float x0 = sin_[k], x1 = sin_[132 + k];
                a00 += x0 * w0; a01 += x0 * w1;
                a10 += x1 * w0; a11 += x1 * w1;
            }
            sh[t] = fmaxf(a00, 0.f); sh[t + 256] = fmaxf(a01, 0.f);
            sh[512 + t] = fmaxf(a10, 0.f); sh[512 + t + 256] = fmaxf(a11, 0.f);
        }
        __syncthreads();
        int j = jh * 256 + t;
        const float* W = role ? W_e1 : W_n1;   // W1h = rows 0..511 of W_e1
        float s0a = 0.f, s0b = 0.f, s1a = 0.f, s1b = 0.f;
        for (int k4 = 0; k4 < HDIM / 4; ++k4) {
            float w0 = W[(size_t)(k4 * 4 + 0) * HDIM + j];
            float w1 = W[(size_t)(k4 * 4 + 1) * HDIM + j];
            float w2 = W[(size_t)(k4 * 4 + 2) * HDIM + j];
            float w3 = W[(size_t)(k4 * 4 + 3) * HDIM + j];
            float4 x0 = *reinterpret_cast<const float4*>(&sh[k4 * 4]);
            float4 x1 = *reinterpret_cast<const float4*>(&sh[512 + k4 * 4]);
            s0a += x0.x * w0 + x0.y * w1;
            s0b += x0.z * w2 + x0.w * w3;
            s1a += x1.x * w0 + x1.y * w1;
            s1b += x1.z * w2 + x1.w * w3;
        }
        float a0 = s0a + s0b, a1 = s1a + s1b;
        if (role == 0) {
            float bb = b_n1[j];
            n1[(size_t)(b0 + 0) * HDIM + j] = fmaxf(a0 + bb, 0.f);
            n1[(size_t)(b0 + 1) * HDIM + j] = fmaxf(a1 + bb, 0.f);
        } else {
            u[(size_t)(b0 + 0) * HDIM + j] = a0;
            u[(size_t)(b0 + 1) * HDIM + j] = a1;
        }
    } else if (bx < 640) {
        int b0 = (bx - 512) * 2;
        float* sin_ = smem;            // [2][132]
        float* sh   = smem + 264;      // [2][512]
        float* s1b  = smem + 264 + 1024;  // [2][256]
        float* slg  = smem + 264 + 1024 + 512;  // [2][50]
        for (int q = t; q < 2 * 131; q += 256) {
            int bi = q / 131, k = q % 131;
            sin_[bi * 132 + k] = (k < LDIM) ? z[(size_t)(b0 + bi) * LDIM + k]
                                            : tp[(size_t)(b0 + bi) * PDIM + (k - LDIM)];
        }
        __syncthreads();
        {
            float bi0 = b_in[t], bi1 = b_in[t + 256];
            float a00 = bi0, a01 = bi1, a10 = bi0, a11 = bi1;
            for (int k = 0; k < LDIM + PDIM; ++k) {
                float w0 = W_in[(size_t)k * HDIM + t];
                float w1 = W_in[(size_t)k * HDIM + t + 256];
                float x0 = sin_[k], x1 = sin_[132 + k];
                a00 += x0 * w0; a01 += x0 * w1;
                a10 += x1 * w0; a11 += x1 * w1;
            }
            sh[t] = fmaxf(a00, 0.f); sh[t + 256] = fmaxf(a01, 0.f);
            sh[512 + t] = fmaxf(a10, 0.f); sh[512 + t + 256] = fmaxf(a11, 0.f);
        }
        __syncthreads();
        {
            float bv = b_s1[t];
            float a0 = bv, a1 = bv;
            for (int k = 0; k < HDIM; ++k) {
                float w = W_s1[(size_t)k * (HDIM / 2) + t];
                a0 += sh[k] * w;
                a1 += sh[512 + k] * w;
            }
            s1b[t] = fmaxf(a0, 0.f);
            s1b[256 + t] = fmaxf(a1, 0.f);
        }
        __syncthreads();
        int b4 = t / NDIM, o = t % NDIM;
        if (t < 2 * NDIM) {
            float a = b_s2[o];
            for (int k = 0; k < HDIM / 2; ++k)
                a += s1b[b4 * 256 + k] * W_s2[(size_t)k * NDIM + o];
            slg[b4 * NDIM + o] = a;
        }
        __syncthreads();
        if (t < 2 * NDIM) {
            float m = slg[b4 * NDIM];
            for (int k = 1; k < NDIM; ++k) m = fmaxf(m, slg[b4 * NDIM + k]);
            float s = 0.f;
            for (int k = 0; k < NDIM; ++k) s += expf(slg[b4 * NDIM + k] - m);
            out_sp[(size_t)(b0 + b4) * NDIM + o] = expf(slg[b4 * NDIM + o] - m) / s;
        }
    } else {
        int g = bx - 640, rg = g >> 1, jh = g & 1;
        int r[4];
#pragma unroll
        for (int q = 0; q < 4; ++q) { int rr = rg * 4 + q; r[q] = (rr < NDIM) ? rr : NDIM - 1; }
        float* spe = smem;   // [4][512]
        for (int q = t; q < 4 * HDIM / 4; q += 256) {
            int lin = q * 4, row = lin >> 9, col = lin & 511;
            *reinterpret_cast<float4*>(&spe[row * HDIM + col]) =
                *reinterpret_cast<const float4*>(&pe[(size_t)r[row] * HDIM + col]);
        }
        __syncthreads();
        int j = jh * 256 + t;
        float a0 = 0.f, a1 = 0.f, a2 = 0.f, a3 = 0.f;
        for (int k4 = 0; k4 < HDIM / 4; ++k4) {
            float w0 = W_e1[(size_t)(k4 * 4 + 0) * HDIM + j];
            float w1 = W_e1[(size_t)(k4 * 4 + 1) * HDIM + j];
            float w2 = W_e1[(size_t)(k4 * 4 + 2) * HDIM + j];
            float w3 = W_e1[(size_t)(k4 * 4 + 3) * HDIM + j];
            float4 x0 = *reinterpret_cast<const float4*>(&spe[0 * HDIM + k4 * 4]);
            float4 x1 = *reinterpret_cast<const float4*>(&spe[1 * HDIM + k4 * 4]);
            float4 x2 = *reinterpret_cast<const float4*>(&spe[2 * HDIM + k4 * 4]);
            float4 x3 = *reinterpret_cast<const float4*>(&spe[3 * HDIM + k4 * 4]);
            a0 += x0.x * w0 + x0.y * w1 + x0.z * w2 + x0.w * w3;
            a1 += x1.x * w0 + x1.y * w1 + x1.z * w2 + x1.w * w3;
            a2 += x2.x * w0 + x2.y * w1 + x2.z * w2 + x2.w * w3;
            a3 += x3.x * w0 + x3.y * w1 + x3.z * w2 + x3.w * w3;
        }
        pW1[(size_t)r[0] * HDIM + j] = 0.5f * a0;
        pW1[(size_t)r[1] * HDIM + j] = 0.5f * a1;
        pW1[(size_t)r[2] * HDIM + j] = 0.5f * a2;
        pW1[(size_t)r[3] * HDIM + j] = 0.5f * a3;
    }
}

// ============ k_nl: [256,512]@[512,1600]+b, 2 batches/block (round-11) =====
__global__ __launch_bounds__(320) void k_nl(const float* __restrict__ n1,
                                            const float* __restrict__ W_n2,
                                            const float* __restrict__ b_n2,
                                            float* __restrict__ out_nl) {
    const int NOUT = NDIM * DDIM;   // 1600
    int t = threadIdx.x;
    int j = blockIdx.y * 320 + t;
    int bg = blockIdx.x;            // 2 batches
    __shared__ float s[2 * HDIM];
    for (int idx = t; idx < 2 * HDIM / 4; idx += 320) {
        int lin = idx * 4;
        int row = lin >> 9, col = lin & 511;
        *reinterpret_cast<float4*>(&s[row * HDIM + col]) =
            *reinterpret_cast<const float4*>(&n1[(size_t)(bg * 2 + row) * HDIM + col]);
    }
    __syncthreads();
    float s0a = 0.f, s0b = 0.f, s1a = 0.f, s1b = 0.f;
    for (int k4 = 0; k4 < HDIM / 4; ++k4) {
        float w0 = W_n2[(size_t)(k4 * 4 + 0) * NOUT + j];
        float w1 = W_n2[(size_t)(k4 * 4 + 1) * NOUT + j];
        float w2 = W_n2[(size_t)(k4 * 4 + 2) * NOUT + j];
        float w3 = W_n2[(size_t)(k4 * 4 + 3) * NOUT + j];
        float4 x0 = *reinterpret_cast<const float4*>(&s[k4 * 4]);
        float4 x1 = *reinterpret_cast<const float4*>(&s[HDIM + k4 * 4]);
        s0a += x0.x * w0 + x0.y * w1;
        s0b += x0.z * w2 + x0.w * w3;
        s1a += x1.x * w0 + x1.y * w1;
        s1b += x1.z * w2 + x1.w * w3;
    }
    float bias = b_n2[j];
    out_nl[(size_t)(bg * 2 + 0) * NOUT + j] = bias + s0a + s0b;
    out_nl[(size_t)(bg * 2 + 1) * NOUT + j] = bias + s1a + s1b;
}

// ============ k_edge: 8 chunks of 64 cols; one produce+consume per block ====
// grid (256,8) = 2048 blocks, block 256, LDS 25.6KB -> up to 6 blocks/CU
// (VGPR <= 85). Produce: (arr, c, rowhalf) x 25 rows. Consume: 225 2x3 tiles
// x 16 r4-iters. P gets 8 partials.
__global__ __launch_bounds__(256) void k_edge(
        const float* __restrict__ nl,    // [256,50,32]
        const float* __restrict__ u,     // [256,512]
        const float* __restrict__ pW1,   // [50,512]
        const float* __restrict__ W_e1,  // [576,512]
        const float* __restrict__ b_e1,  // [512]
        const float* __restrict__ W_e2,  // [512,5]
        float* __restrict__ P) {         // [8][256][1225][5]
    int b  = blockIdx.x;
    int rh = blockIdx.y;
    int t  = threadIdx.x;
    int rbase = rh * ECH;

    __shared__ float As[NDIM * ECH];   // 12.8 KB
    __shared__ float Bs[NDIM * ECH];   // 12.8 KB

    // task decode: (p,q): rows i0=2p,i0+1; cols j0=3q..3q+2; 225 valid tiles
    bool has = (t < 225);
    int pp = 0, qq = 0;
    if (has) {
        int tt = t;
        for (pp = 0; pp < 25; ++pp) {
            int qmin = pp ? ((2 * pp - 2) / 3 + 1) : 0;
            int cnt = 17 - qmin;
            if (tt < cnt) { qq = qmin + tt; break; }
            tt -= cnt;
        }
    }
    int i0 = 2 * pp, i1 = i0 + 1;
    int j0 = 3 * qq, j1 = j0 + 1, j2r = (3 * qq + 2 < NDIM) ? 3 * qq + 2 : NDIM - 1;

    float acc[6][EOUT];
#pragma unroll
    for (int e = 0; e < 6; ++e)
#pragma unroll
        for (int o = 0; o < EOUT; ++o) acc[e][o] = 0.f;

    // ---- produce: c = t&63, arr = (t>>6)&1, nh = t>>7 (25 rows each) ----
    {
        int c = t & 63, arr = (t >> 6) & 1, nh = t >> 7;
        int col = rbase + c;
        const float4* nl4 = reinterpret_cast<const float4*>(nl + (size_t)b * (NDIM * DDIM));
        float w[DDIM];
#pragma unroll
        for (int k = 0; k < DDIM; ++k)
            w[k] = W_e1[(size_t)(HDIM + arr * DDIM + k) * HDIM + col];
        float cm = 0.5f * (u[(size_t)b * HDIM + col] + b_e1[col]);
        float* dst = arr ? Bs : As;
        int n0 = nh * 25;
        float pc = pW1[(size_t)n0 * HDIM + col];
        for (int k = 0; k < 25; ++k) {
            int n = n0 + k;
            float pn = (k < 24) ? pW1[(size_t)(n + 1) * HDIM + col] : 0.f;
            float s0 = 0.f, s1 = 0.f, s2 = 0.f, s3 = 0.f;
#pragma unroll
            for (int h = 0; h < 2; ++h) {
                int q = h * 4;
                float4 xA = nl4[n * 8 + q + 0];
                float4 xB = nl4[n * 8 + q + 1];
                float4 xC = nl4[n * 8 + q + 2];
                float4 xD = nl4[n * 8 + q + 3];
                s0 += xA.x * w[4*q+0]  + xA.y * w[4*q+1]  + xA.z * w[4*q+2]  + xA.w * w[4*q+3];
                s1 += xB.x * w[4*q+4]  + xB.y * w[4*q+5]  + xB.z * w[4*q+6]  + xB.w * w[4*q+7];
                s2 += xC.x * w[4*q+8]  + xC.y * w[4*q+9]  + xC.z * w[4*q+10] + xC.w * w[4*q+11];
                s3 += xD.x * w[4*q+12] + xD.y * w[4*q+13] + xD.z * w[4*q+14] + xD.w * w[4*q+15];
            }
            dst[n * ECH + ((((c >> 2) ^ (n & 7)) << 2) | (c & 3))] =
                (cm + pc) + ((s0 + s1) + (s2 + s3));
            pc = pn;
        }
    }
    __syncthreads();

    // ---- consume ----
    if (has) {
        const float4* A4 = reinterpret_cast<const float4*>(As);
        const float4* B4 = reinterpret_cast<const float4*>(Bs);
        const float* wch = W_e2 + (size_t)rbase * EOUT;
        const int e4 = ECH / 4;   // 16
        int iA = i0 * e4, iB = i1 * e4;
        int jA = j0 * e4, jB = j1 * e4, jC = j2r * e4;
        int sA = i0 & 7, sB = i1 & 7, s0m = j0 & 7, s1m = j1 & 7, s2m = j2r & 7;
        for (int r4 = 0; r4 < e4; ++r4) {
            const float* wr = wch + r4 * 4 * EOUT;   // uniform -> s_load
            float4 a0 = A4[iA + (r4 ^ sA)];
            float4 a1 = A4[iB + (r4 ^ sB)];
            float4 b0 = B4[jA + (r4 ^ s0m)];
            float4 b1 = B4[jB + (r4 ^ s1m)];
            float4 b2 = B4[jC + (r4 ^ s2m)];
            float v[6][4];
#pragma unroll
            for (int rr = 0; rr < 4; ++rr) {
                float av0 = (&a0.x)[rr], av1 = (&a1.x)[rr];
                float bv0 = (&b0.x)[rr], bv1 = (&b1.x)[rr], bv2 = (&b2.x)[rr];
                v[0][rr] = fmaxf(av0 + bv0, 0.f);
                v[1][rr] = fmaxf(av0 + bv1, 0.f);
                v[2][rr] = fmaxf(av0 + bv2, 0.f);
                v[3][rr] = fmaxf(av1 + bv0, 0.f);
                v[4][rr] = fmaxf(av1 + bv1, 0.f);
                v[5][rr] = fmaxf(av1 + bv2, 0.f);
            }
#pragma unroll
            for (int rr = 0; rr < 4; ++rr) {
#pragma unroll
                for (int o = 0; o < EOUT; ++o) {
                    float wv = wr[rr * EOUT + o];
#pragma unroll
                    for (int e = 0; e < 6; ++e)
                        acc[e][o] += v[e][rr] * wv;
                }
            }
        }
    }
    __syncthreads();

    if (has) {
        float* Pb = P + ((size_t)rh * BSZ + b) * NEDGE * EOUT;
        int js[3] = {j0, j1, 3 * qq + 2};
#pragma unroll
        for (int r = 0; r < 2; ++r) {
            int i = i0 + r;
#pragma unroll
            for (int cc = 0; cc < 3; ++cc) {
                int j = js[cc];
                if (i < j && j < NDIM) {
                    int e = i * (NDIM - 1) - (i * (i - 1)) / 2 + (j - i - 1);
#pragma unroll
                    for (int o = 0; o < EOUT; ++o)
                        Pb[(size_t)e * EOUT + o] = acc[r * 3 + cc][o];
                }
            }
        }
    }
}

// ============ k_comb: out_el = sum of 8 partials + bias ====================
__global__ __launch_bounds__(256) void k_comb(const float* __restrict__ P,
                                              const float* __restrict__ b_e2,
                                              float* __restrict__ out_el,
                                              float* __restrict__ out_idx) {
    int blk = blockIdx.x, t = threadIdx.x;
    const size_t PS = (size_t)BSZ * NEDGE * EOUT;
    if (blk < 307) {
        int tid = blk * 256 + t;       // 20 floats per thread; 78400 total
        if (tid < 78400) {
            float b5[5];
#pragma unroll
            for (int cc = 0; cc < 5; ++cc) b5[cc] = b_e2[cc];
#pragma unroll
            for (int q = 0; q < 5; ++q) {
                float4 s = make_float4(0.f, 0.f, 0.f, 0.f);
#pragma unroll
                for (int p = 0; p < 8; ++p) {
                    float4 v = reinterpret_cast<const float4*>(P + (size_t)p * PS)[(size_t)tid * 5 + q];
                    s.x += v.x; s.y += v.y; s.z += v.z; s.w += v.w;
                }
                float4 r;
                r.x = s.x + b5[(q * 4 + 0) % 5];
                r.y = s.y + b5[(q * 4 + 1) % 5];
                r.z = s.z + b5[(q * 4 + 2) % 5];
                r.w = s.w + b5[(q * 4 + 3) % 5];
                reinterpret_cast<float4*>(out_el)[(size_t)tid * 5 + q] = r;
            }
        }
    } else {
        int e = (blk - 307) * 256 + t;
        if (e < NEDGE) {
            int i = 0, rem = e;
            while (rem >= (NDIM - 1 - i)) { rem -= (NDIM - 1 - i); ++i; }
            int j = i + 1 + rem;
            out_idx[e * 2] = (float)i;
            out_idx[e * 2 + 1] = (float)j;
        }
    }
}

extern "C" void kernel_launch(void* const* d_in, const int* in_sizes, int n_in,
                              void* d_out, int out_size, void* d_ws, size_t ws_size,
                              hipStream_t stream) {
    const float* z    = (const float*)d_in[0];
    const float* tp   = (const float*)d_in[1];
    const float* W_in = (const float*)d_in[2];
    const float* b_in = (const float*)d_in[3];
    const float* W_s1 = (const float*)d_in[4];
    const float* b_s1 = (const float*)d_in[5];
    const float* W_s2 = (const float*)d_in[6];
    const float* b_s2 = (const float*)d_in[7];
    const float* W_n1 = (const float*)d_in[8];
    const float* b_n1 = (const float*)d_in[9];
    const float* W_n2 = (const float*)d_in[10];
    const float* b_n2 = (const float*)d_in[11];
    const float* W_e1 = (const float*)d_in[12];
    const float* b_e1 = (const float*)d_in[13];
    const float* W_e2 = (const float*)d_in[14];
    const float* b_e2 = (const float*)d_in[15];
    const float* pe   = (const float*)d_in[16];

    float* out     = (float*)d_out;
    float* out_nl  = out;                 // node_logits
    float* out_el  = out + 409600;        // edge_logits
    float* out_sp  = out + 1977600;       // size_probs
    float* out_idx = out + 1990400;       // edge_indices (as float)

    float* ws  = (float*)d_ws;
    float* u   = ws;
    float* pW1 = ws + 131072;
    float* n1  = ws + 156672;
    float* P   = ws + 287744;             // [8][256][1225][5]

    k_pre<<<666, 256, 0, stream>>>(z, tp, W_in, b_in, W_s1, b_s1, W_s2, b_s2,
                                   W_n1, b_n1, W_e1, pe, n1, u, pW1, out_sp);
    k_nl<<<dim3(128, 5), 320, 0, stream>>>(n1, W_n2, b_n2, out_nl);
    k_edge<<<dim3(BSZ, NRH), 256, 0, stream>>>(out_nl, u, pW1, W_e1, b_e1, W_e2, P);
    k_comb<<<312, 256, 0, stream>>>(P, b_e2, out_el, out_idx);
}

// Round 13
// 160.562 us; speedup vs baseline: 1.2151x; 1.2151x over previous
//
#include <hip/hip_runtime.h>
#include <math.h>

// Problem dims
#define BSZ   256
#define LDIM  128
#define PDIM  3
#define HDIM  512
#define DDIM  32
#define NDIM  50
#define NEDGE 1225   // N*(N-1)/2
#define EOUT  5      // EDIM+1
#define NRH   3      // r-splits: cols {192,192,128}

// out layout (floats)
//   node_logits  [256,50,32]   @ 0        (409600)
//   edge_logits  [256,1225,5]  @ 409600   (1568000)
//   size_probs   [256,50]      @ 1977600  (12800)
//   edge_indices [1225,2]      @ 1990400  (2450, float values)
// ws layout (floats): u @0 (131072), pW1 @131072 (25600), n1 @156672 (131072),
//                     P @287744 (3 x 1568000)

// ============ k_pre: 256-thr blocks, col-split roles (round-11, proven) ====
__global__ __launch_bounds__(256) void k_pre(
        const float* __restrict__ z, const float* __restrict__ tp,
        const float* __restrict__ W_in, const float* __restrict__ b_in,
        const float* __restrict__ W_s1, const float* __restrict__ b_s1,
        const float* __restrict__ W_s2, const float* __restrict__ b_s2,
        const float* __restrict__ W_n1, const float* __restrict__ b_n1,
        const float* __restrict__ W_e1, const float* __restrict__ pe,
        float* __restrict__ n1, float* __restrict__ u,
        float* __restrict__ pW1, float* __restrict__ out_sp) {
    int bx = blockIdx.x, t = threadIdx.x;
    __shared__ float smem[2368];

    if (bx < 512) {
        int role = bx >> 8;
        int idx2 = bx & 255;
        int bg = idx2 >> 1, jh = idx2 & 1;
        int b0 = bg * 2;
        float* sin_ = smem;            // [2][132]
        float* sh   = smem + 264;      // [2][512]
        for (int q = t; q < 2 * 131; q += 256) {
            int bi = q / 131, k = q % 131;
            sin_[bi * 132 + k] = (k < LDIM) ? z[(size_t)(b0 + bi) * LDIM + k]
                                            : tp[(size_t)(b0 + bi) * PDIM + (k - LDIM)];
        }
        __syncthreads();
        {
            float bi0 = b_in[t], bi1 = b_in[t + 256];
            float a00 = bi0, a01 = bi1, a10 = bi0, a11 = bi1;
            for (int k = 0; k < LDIM + PDIM; ++k) {
                float w0 = W_in[(size_t)k * HDIM + t];
                float w1 = W_in[(size_t)k * HDIM + t + 256];
                float x0 = sin_[k], x1 = sin_[132 + k];
                a00 += x0 * w0; a01 += x0 * w1;
                a10 += x1 * w0; a11 += x1 * w1;
            }
            sh[t] = fmaxf(a00, 0.f); sh[t + 256] = fmaxf(a01, 0.f);
            sh[512 + t] = fmaxf(a10, 0.f); sh[512 + t + 256] = fmaxf(a11, 0.f);
        }
        __syncthreads();
        int j = jh * 256 + t;
        const float* W = role ? W_e1 : W_n1;   // W1h = rows 0..511 of W_e1
        float s0a = 0.f, s0b = 0.f, s1a = 0.f, s1b = 0.f;
        for (int k4 = 0; k4 < HDIM / 4; ++k4) {
            float w0 = W[(size_t)(k4 * 4 + 0) * HDIM + j];
            float w1 = W[(size_t)(k4 * 4 + 1) * HDIM + j];
            float w2 = W[(size_t)(k4 * 4 + 2) * HDIM + j];
            float w3 = W[(size_t)(k4 * 4 + 3) * HDIM + j];
            float4 x0 = *reinterpret_cast<const float4*>(&sh[k4 * 4]);
            float4 x1 = *reinterpret_cast<const float4*>(&sh[512 + k4 * 4]);
            s0a += x0.x * w0 + x0.y * w1;
            s0b += x0.z * w2 + x0.w * w3;
            s1a += x1.x * w0 + x1.y * w1;
            s1b += x1.z * w2 + x1.w * w3;
        }
        float a0 = s0a + s0b, a1 = s1a + s1b;
        if (role == 0) {
            float bb = b_n1[j];
            n1[(size_t)(b0 + 0) * HDIM + j] = fmaxf(a0 + bb, 0.f);
            n1[(size_t)(b0 + 1) * HDIM + j] = fmaxf(a1 + bb, 0.f);
        } else {
            u[(size_t)(b0 + 0) * HDIM + j] = a0;
            u[(size_t)(b0 + 1) * HDIM + j] = a1;
        }
    } else if (bx < 640) {
        int b0 = (bx - 512) * 2;
        float* sin_ = smem;            // [2][132]
        float* sh   = smem + 264;      // [2][512]
        float* s1b  = smem + 264 + 1024;  // [2][256]
        float* slg  = smem + 264 + 1024 + 512;  // [2][50]
        for (int q = t; q < 2 * 131; q += 256) {
            int bi = q / 131, k = q % 131;
            sin_[bi * 132 + k] = (k < LDIM) ? z[(size_t)(b0 + bi) * LDIM + k]
                                            : tp[(size_t)(b0 + bi) * PDIM + (k - LDIM)];
        }
        __syncthreads();
        {
            float bi0 = b_in[t], bi1 = b_in[t + 256];
            float a00 = bi0, a01 = bi1, a10 = bi0, a11 = bi1;
            for (int k = 0; k < LDIM + PDIM; ++k) {
                float w0 = W_in[(size_t)k * HDIM + t];
                float w1 = W_in[(size_t)k * HDIM + t + 256];
                float x0 = sin_[k], x1 = sin_[132 + k];
                a00 += x0 * w0; a01 += x0 * w1;
                a10 += x1 * w0; a11 += x1 * w1;
            }
            sh[t] = fmaxf(a00, 0.f); sh[t + 256] = fmaxf(a01, 0.f);
            sh[512 + t] = fmaxf(a10, 0.f); sh[512 + t + 256] = fmaxf(a11, 0.f);
        }
        __syncthreads();
        {
            float bv = b_s1[t];
            float a0 = bv, a1 = bv;
            for (int k = 0; k < HDIM; ++k) {
                float w = W_s1[(size_t)k * (HDIM / 2) + t];
                a0 += sh[k] * w;
                a1 += sh[512 + k] * w;
            }
            s1b[t] = fmaxf(a0, 0.f);
            s1b[256 + t] = fmaxf(a1, 0.f);
        }
        __syncthreads();
        int b4 = t / NDIM, o = t % NDIM;
        if (t < 2 * NDIM) {
            float a = b_s2[o];
            for (int k = 0; k < HDIM / 2; ++k)
                a += s1b[b4 * 256 + k] * W_s2[(size_t)k * NDIM + o];
            slg[b4 * NDIM + o] = a;
        }
        __syncthreads();
        if (t < 2 * NDIM) {
            float m = slg[b4 * NDIM];
            for (int k = 1; k < NDIM; ++k) m = fmaxf(m, slg[b4 * NDIM + k]);
            float s = 0.f;
            for (int k = 0; k < NDIM; ++k) s += expf(slg[b4 * NDIM + k] - m);
            out_sp[(size_t)(b0 + b4) * NDIM + o] = expf(slg[b4 * NDIM + o] - m) / s;
        }
    } else {
        int g = bx - 640, rg = g >> 1, jh = g & 1;
        int r[4];
#pragma unroll
        for (int q = 0; q < 4; ++q) { int rr = rg * 4 + q; r[q] = (rr < NDIM) ? rr : NDIM - 1; }
        float* spe = smem;   // [4][512]
        for (int q = t; q < 4 * HDIM / 4; q += 256) {
            int lin = q * 4, row = lin >> 9, col = lin & 511;
            *reinterpret_cast<float4*>(&spe[row * HDIM + col]) =
                *reinterpret_cast<const float4*>(&pe[(size_t)r[row] * HDIM + col]);
        }
        __syncthreads();
        int j = jh * 256 + t;
        float a0 = 0.f, a1 = 0.f, a2 = 0.f, a3 = 0.f;
        for (int k4 = 0; k4 < HDIM / 4; ++k4) {
            float w0 = W_e1[(size_t)(k4 * 4 + 0) * HDIM + j];
            float w1 = W_e1[(size_t)(k4 * 4 + 1) * HDIM + j];
            float w2 = W_e1[(size_t)(k4 * 4 + 2) * HDIM + j];
            float w3 = W_e1[(size_t)(k4 * 4 + 3) * HDIM + j];
            float4 x0 = *reinterpret_cast<const float4*>(&spe[0 * HDIM + k4 * 4]);
            float4 x1 = *reinterpret_cast<const float4*>(&spe[1 * HDIM + k4 * 4]);
            float4 x2 = *reinterpret_cast<const float4*>(&spe[2 * HDIM + k4 * 4]);
            float4 x3 = *reinterpret_cast<const float4*>(&spe[3 * HDIM + k4 * 4]);
            a0 += x0.x * w0 + x0.y * w1 + x0.z * w2 + x0.w * w3;
            a1 += x1.x * w0 + x1.y * w1 + x1.z * w2 + x1.w * w3;
            a2 += x2.x * w0 + x2.y * w1 + x2.z * w2 + x2.w * w3;
            a3 += x3.x * w0 + x3.y * w1 + x3.z * w2 + x3.w * w3;
        }
        pW1[(size_t)r[0] * HDIM + j] = 0.5f * a0;
        pW1[(size_t)r[1] * HDIM + j] = 0.5f * a1;
        pW1[(size_t)r[2] * HDIM + j] = 0.5f * a2;
        pW1[(size_t)r[3] * HDIM + j] = 0.5f * a3;
    }
}

// ============ k_nl: [256,512]@[512,1600]+b, 2 batches/block (round-11) =====
__global__ __launch_bounds__(320) void k_nl(const float* __restrict__ n1,
                                            const float* __restrict__ W_n2,
                                            const float* __restrict__ b_n2,
                                            float* __restrict__ out_nl) {
    const int NOUT = NDIM * DDIM;   // 1600
    int t = threadIdx.x;
    int j = blockIdx.y * 320 + t;
    int bg = blockIdx.x;            // 2 batches
    __shared__ float s[2 * HDIM];
    for (int idx = t; idx < 2 * HDIM / 4; idx += 320) {
        int lin = idx * 4;
        int row = lin >> 9, col = lin & 511;
        *reinterpret_cast<float4*>(&s[row * HDIM + col]) =
            *reinterpret_cast<const float4*>(&n1[(size_t)(bg * 2 + row) * HDIM + col]);
    }
    __syncthreads();
    float s0a = 0.f, s0b = 0.f, s1a = 0.f, s1b = 0.f;
    for (int k4 = 0; k4 < HDIM / 4; ++k4) {
        float w0 = W_n2[(size_t)(k4 * 4 + 0) * NOUT + j];
        float w1 = W_n2[(size_t)(k4 * 4 + 1) * NOUT + j];
        float w2 = W_n2[(size_t)(k4 * 4 + 2) * NOUT + j];
        float w3 = W_n2[(size_t)(k4 * 4 + 3) * NOUT + j];
        float4 x0 = *reinterpret_cast<const float4*>(&s[k4 * 4]);
        float4 x1 = *reinterpret_cast<const float4*>(&s[HDIM + k4 * 4]);
        s0a += x0.x * w0 + x0.y * w1;
        s0b += x0.z * w2 + x0.w * w3;
        s1a += x1.x * w0 + x1.y * w1;
        s1b += x1.z * w2 + x1.w * w3;
    }
    float bias = b_n2[j];
    out_nl[(size_t)(bg * 2 + 0) * NOUT + j] = bias + s0a + s0b;
    out_nl[(size_t)(bg * 2 + 1) * NOUT + j] = bias + s1a + s1b;
}

// ============ k_edge: round-11 shape + nl staged in LDS ====================
// grid (256,3), block 256, LDS 44.8KB -> 3 blocks/CU.
// Produce reads nl via ds_read broadcast (was scalar s_load chains).
template<int ECH>
__device__ __forceinline__ void edge_chunk(
        int b, int rh, int rbase, int t,
        const float* __restrict__ u, const float* __restrict__ pW1,
        const float* __restrict__ W_e1, const float* __restrict__ b_e1,
        const float* __restrict__ W_e2, float* __restrict__ P,
        float* As, float* Bs, const float4* nls4) {
    // task decode: (p,q): rows i0=2p,i0+1; cols j0=3q..3q+2; 225 valid tiles
    bool has = (t < 225);
    int pp = 0, qq = 0;
    if (has) {
        int tt = t;
        for (pp = 0; pp < 25; ++pp) {
            int qmin = pp ? ((2 * pp - 2) / 3 + 1) : 0;
            int cnt = 17 - qmin;
            if (tt < cnt) { qq = qmin + tt; break; }
            tt -= cnt;
        }
    }
    int i0 = 2 * pp, i1 = i0 + 1;
    int j0 = 3 * qq, j1 = j0 + 1, j2r = (3 * qq + 2 < NDIM) ? 3 * qq + 2 : NDIM - 1;

    float acc[6][EOUT];
#pragma unroll
    for (int e = 0; e < 6; ++e)
#pragma unroll
        for (int o = 0; o < EOUT; ++o) acc[e][o] = 0.f;

    bool prod = (t < 2 * ECH);
    int arr = (t >= ECH) ? 1 : 0;
    int c = t - (arr ? ECH : 0);

    for (int ch = 0; ch < 2; ++ch) {
        // ---- produce (nl from LDS broadcast) ----
        if (prod) {
            int col = rbase + ch * ECH + c;
            float w[DDIM];
#pragma unroll
            for (int k = 0; k < DDIM; ++k)
                w[k] = W_e1[(size_t)(HDIM + arr * DDIM + k) * HDIM + col];
            float cm = 0.5f * (u[(size_t)b * HDIM + col] + b_e1[col]);
            float* dst = arr ? Bs : As;
            float pc = pW1[col];
            for (int n = 0; n < NDIM; ++n) {
                float pn = (n < NDIM - 1) ? pW1[(size_t)(n + 1) * HDIM + col] : 0.f;
                float s0 = 0.f, s1 = 0.f, s2 = 0.f, s3 = 0.f;
#pragma unroll
                for (int h = 0; h < 2; ++h) {
                    int q = h * 4;
                    float4 xA = nls4[n * 8 + q + 0];
                    float4 xB = nls4[n * 8 + q + 1];
                    float4 xC = nls4[n * 8 + q + 2];
                    float4 xD = nls4[n * 8 + q + 3];
                    s0 += xA.x * w[4*q+0]  + xA.y * w[4*q+1]  + xA.z * w[4*q+2]  + xA.w * w[4*q+3];
                    s1 += xB.x * w[4*q+4]  + xB.y * w[4*q+5]  + xB.z * w[4*q+6]  + xB.w * w[4*q+7];
                    s2 += xC.x * w[4*q+8]  + xC.y * w[4*q+9]  + xC.z * w[4*q+10] + xC.w * w[4*q+11];
                    s3 += xD.x * w[4*q+12] + xD.y * w[4*q+13] + xD.z * w[4*q+14] + xD.w * w[4*q+15];
                }
                dst[n * ECH + ((((c >> 2) ^ (n & 7)) << 2) | (c & 3))] =
                    (cm + pc) + ((s0 + s1) + (s2 + s3));
                pc = pn;
            }
        }
        __syncthreads();
        // ---- consume (compile-time trip count) ----
        if (has) {
            const float4* A4 = reinterpret_cast<const float4*>(As);
            const float4* B4 = reinterpret_cast<const float4*>(Bs);
            const float* wch = W_e2 + (size_t)(rbase + ch * ECH) * EOUT;
            const int e4 = ECH / 4;
            int iA = i0 * e4, iB = i1 * e4;
            int jA = j0 * e4, jB = j1 * e4, jC = j2r * e4;
            int sA = i0 & 7, sB = i1 & 7, s0m = j0 & 7, s1m = j1 & 7, s2m = j2r & 7;
#pragma unroll 4
            for (int r4 = 0; r4 < e4; ++r4) {
                const float* wr = wch + r4 * 4 * EOUT;   // uniform -> s_load
                float4 a0 = A4[iA + (r4 ^ sA)];
                float4 a1 = A4[iB + (r4 ^ sB)];
                float4 b0 = B4[jA + (r4 ^ s0m)];
                float4 b1 = B4[jB + (r4 ^ s1m)];
                float4 b2 = B4[jC + (r4 ^ s2m)];
                float v[6][4];
#pragma unroll
                for (int rr = 0; rr < 4; ++rr) {
                    float av0 = (&a0.x)[rr], av1 = (&a1.x)[rr];
                    float bv0 = (&b0.x)[rr], bv1 = (&b1.x)[rr], bv2 = (&b2.x)[rr];
                    v[0][rr] = fmaxf(av0 + bv0, 0.f);
                    v[1][rr] = fmaxf(av0 + bv1, 0.f);
                    v[2][rr] = fmaxf(av0 + bv2, 0.f);
                    v[3][rr] = fmaxf(av1 + bv0, 0.f);
                    v[4][rr] = fmaxf(av1 + bv1, 0.f);
                    v[5][rr] = fmaxf(av1 + bv2, 0.f);
                }
#pragma unroll
                for (int rr = 0; rr < 4; ++rr) {
#pragma unroll
                    for (int o = 0; o < EOUT; ++o) {
                        float wv = wr[rr * EOUT + o];
#pragma unroll
                        for (int e = 0; e < 6; ++e)
                            acc[e][o] += v[e][rr] * wv;
                    }
                }
            }
        }
        __syncthreads();
    }

    if (has) {
        float* Pb = P + ((size_t)rh * BSZ + b) * NEDGE * EOUT;
        int js[3] = {j0, j1, 3 * qq + 2};
#pragma unroll
        for (int r = 0; r < 2; ++r) {
            int i = i0 + r;
#pragma unroll
            for (int cc = 0; cc < 3; ++cc) {
                int j = js[cc];
                if (i < j && j < NDIM) {
                    int e = i * (NDIM - 1) - (i * (i - 1)) / 2 + (j - i - 1);
#pragma unroll
                    for (int o = 0; o < EOUT; ++o)
                        Pb[(size_t)e * EOUT + o] = acc[r * 3 + cc][o];
                }
            }
        }
    }
}

__global__ __launch_bounds__(256) void k_edge(
        const float* __restrict__ nl,    // [256,50,32]
        const float* __restrict__ u,     // [256,512]
        const float* __restrict__ pW1,   // [50,512]
        const float* __restrict__ W_e1,  // [576,512]
        const float* __restrict__ b_e1,  // [512]
        const float* __restrict__ W_e2,  // [512,5]
        float* __restrict__ P) {         // [3][256][1225][5]
    int b  = blockIdx.x;
    int rh = blockIdx.y;
    int t  = threadIdx.x;

    __shared__ float As[NDIM * 96];        // 19.2 KB
    __shared__ float Bs[NDIM * 96];        // 19.2 KB
    __shared__ float4 nls4[NDIM * 8];      // 6.4 KB

    // stage nl[b] into LDS (coalesced vector loads)
    const float4* g = reinterpret_cast<const float4*>(nl + (size_t)b * (NDIM * DDIM));
    for (int i = t; i < NDIM * 8; i += 256) nls4[i] = g[i];
    __syncthreads();

    if (rh < 2)
        edge_chunk<96>(b, rh, rh * 192, t, u, pW1, W_e1, b_e1, W_e2, P, As, Bs, nls4);
    else
        edge_chunk<64>(b, rh, 384, t, u, pW1, W_e1, b_e1, W_e2, P, As, Bs, nls4);
}

// ============ k_comb: out_el = P0+P1+P2 + bias (float4 x5/thread) ==========
__global__ __launch_bounds__(256) void k_comb(const float* __restrict__ P,
                                              const float* __restrict__ b_e2,
                                              float* __restrict__ out_el,
                                              float* __restrict__ out_idx) {
    int blk = blockIdx.x, t = threadIdx.x;
    const size_t PS = (size_t)BSZ * NEDGE * EOUT;
    if (blk < 307) {
        int tid = blk * 256 + t;       // 20 floats per thread; 78400 total
        if (tid < 78400) {
            const float4* p0 = reinterpret_cast<const float4*>(P) + (size_t)tid * 5;
            const float4* p1 = reinterpret_cast<const float4*>(P + PS) + (size_t)tid * 5;
            const float4* p2 = reinterpret_cast<const float4*>(P + 2 * PS) + (size_t)tid * 5;
            float4* o = reinterpret_cast<float4*>(out_el) + (size_t)tid * 5;
            float b5[5];
#pragma unroll
            for (int cc = 0; cc < 5; ++cc) b5[cc] = b_e2[cc];
#pragma unroll
            for (int q = 0; q < 5; ++q) {
                float4 a = p0[q], b = p1[q], cq = p2[q];
                float4 r;
                r.x = a.x + b.x + cq.x + b5[(q * 4 + 0) % 5];
                r.y = a.y + b.y + cq.y + b5[(q * 4 + 1) % 5];
                r.z = a.z + b.z + cq.z + b5[(q * 4 + 2) % 5];
                r.w = a.w + b.w + cq.w + b5[(q * 4 + 3) % 5];
                o[q] = r;
            }
        }
    } else {
        int e = (blk - 307) * 256 + t;
        if (e < NEDGE) {
            int i = 0, rem = e;
            while (rem >= (NDIM - 1 - i)) { rem -= (NDIM - 1 - i); ++i; }
            int j = i + 1 + rem;
            out_idx[e * 2] = (float)i;
            out_idx[e * 2 + 1] = (float)j;
        }
    }
}

extern "C" void kernel_launch(void* const* d_in, const int* in_sizes, int n_in,
                              void* d_out, int out_size, void* d_ws, size_t ws_size,
                              hipStream_t stream) {
    const float* z    = (const float*)d_in[0];
    const float* tp   = (const float*)d_in[1];
    const float* W_in = (const float*)d_in[2];
    const float* b_in = (const float*)d_in[3];
    const float* W_s1 = (const float*)d_in[4];
    const float* b_s1 = (const float*)d_in[5];
    const float* W_s2 = (const float*)d_in[6];
    const float* b_s2 = (const float*)d_in[7];
    const float* W_n1 = (const float*)d_in[8];
    const float* b_n1 = (const float*)d_in[9];
    const float* W_n2 = (const float*)d_in[10];
    const float* b_n2 = (const float*)d_in[11];
    const float* W_e1 = (const float*)d_in[12];
    const float* b_e1 = (const float*)d_in[13];
    const float* W_e2 = (const float*)d_in[14];
    const float* b_e2 = (const float*)d_in[15];
    const float* pe   = (const float*)d_in[16];

    float* out     = (float*)d_out;
    float* out_nl  = out;                 // node_logits
    float* out_el  = out + 409600;        // edge_logits
    float* out_sp  = out + 1977600;       // size_probs
    float* out_idx = out + 1990400;       // edge_indices (as float)

    float* ws  = (float*)d_ws;
    float* u   = ws;
    float* pW1 = ws + 131072;
    float* n1  = ws + 156672;
    float* P   = ws + 287744;             // [3][256][1225][5]

    k_pre<<<666, 256, 0, stream>>>(z, tp, W_in, b_in, W_s1, b_s1, W_s2, b_s2,
                                   W_n1, b_n1, W_e1, pe, n1, u, pW1, out_sp);
    k_nl<<<dim3(128, 5), 320, 0, stream>>>(n1, W_n2, b_n2, out_nl);
    k_edge<<<dim3(BSZ, NRH), 256, 0, stream>>>(out_nl, u, pW1, W_e1, b_e1, W_e2, P);
    k_comb<<<312, 256, 0, stream>>>(P, b_e2, out_el, out_idx);
}